// Round 6
// baseline (327.010 us; speedup 1.0000x reference)
//
#include <hip/hip_runtime.h>

typedef unsigned short ushort_t;
typedef __attribute__((ext_vector_type(4))) unsigned short ushort4_t;
typedef __attribute__((ext_vector_type(8))) short short8;
typedef __attribute__((ext_vector_type(4))) unsigned int uint4v;
typedef __attribute__((ext_vector_type(2))) float float2v;
typedef __attribute__((ext_vector_type(4))) float floatx4;
typedef __attribute__((ext_vector_type(16))) float floatx16;

#define B_ 4
#define C_ 256
#define R_ 256
#define M_ 40
#define NCLS 21
#define ROI_ 7
#define G_ 14
#define NROI_TOT 3072
#define PROPS_PER_IMG 768
#define POOL_PITCH 264   // ushorts per pool row (528 B, 16B-aligned) [R8 proven best]
#define POOL_ROWS 148    // 3 rois x 49 positions + 1 shared zero row
#define WCONV_ELEMS (256 * 2304)   // = 144 chunks * 4096
#define NKB 392                    // 12544 / 32 k-blocks for FC
#define WFC2_ELEMS (NKB * 32 * 32) // padded 32 classes, fragment-ordered
// ws layout (ushort offsets)
#define OFF_FWB   WCONV_ELEMS
#define OFF_CL3   (OFF_FWB + WFC2_ELEMS)
#define OFF_CL4   (OFF_CL3 + 4 * 64 * 64 * 256)
#define OFF_CL5   (OFF_CL4 + 4 * 32 * 32 * 256)

// LEDGER (falsified experiments — do not retry):
//  R3 stagger (per-CU ticket + 18us sleep): +8 us. Forced de-phasing only
//     added idle; natural drift already interleaves co-resident blocks.
//  R4 fp32 feature staging: VALU drop as predicted, but FETCH 18.3->32 MB
//     (features 2.6->5.2 MB/img vs 4 MiB XCD L2) -> net +19 us.
//  R5 calibration: identical code re-bench spread ~2.7% (247.4 vs 254.1).
// R6: s_pool XOR swizzle. Pitch 528 B = 132 dw = 4 banks/row -> rows bn,bn+8
//  share bank-start; conv b128 reads are ~4-way conflicted (1.73e7 cycles
//  = ~28 us/CU). col16 ^= ((row>>3)&3)<<1 dealises {bn,bn+8,bn+16,bn+24}
//  to bank-starts 0/8/16/24. Write+read both swizzled (involution).

__device__ __forceinline__ ushort_t f2bf(float f) {
  unsigned u = __builtin_bit_cast(unsigned, f);
  u += 0x7fff + ((u >> 16) & 1);  // RNE
  return (ushort_t)(u >> 16);
}
// two packed bf16 (one dword) -> float2 {low half, high half}
__device__ __forceinline__ float2v cvt2(unsigned u) {
  float2v r;
  r[0] = __builtin_bit_cast(float, u << 16);
  r[1] = __builtin_bit_cast(float, u & 0xffff0000u);
  return r;
}
// ushort-index column swizzle within a pool row (32B granular XOR)
__device__ __forceinline__ int pswz(int row, int col_us) {
  return col_us ^ (((row >> 3) & 3) << 4);
}

// ---------------------------------------------------------------------------
// NCHW fp32 -> NHWC bf16 transpose for one (b, y) feature row, compile-time W.
// ---------------------------------------------------------------------------
template <int W>
__device__ __forceinline__ void transpose_feat(const float* __restrict__ in,
                                               ushort_t* __restrict__ outp,
                                               const int fid, const int t,
                                               ushort_t* __restrict__ tile) {
  const int b = fid / W;
  const int y = fid - b * W;
  const float* src = in + (size_t)(b * 256) * (W * W) + (size_t)y * W;
#pragma unroll
  for (int i = 0; i < W / 4; ++i) {
    const int f4 = t + i * 256;
    const int c = f4 / (W / 4);
    const int x = (f4 - c * (W / 4)) * 4;
    const floatx4 v = *(const floatx4*)(src + (size_t)c * (W * W) + x);
    tile[c * 65 + x + 0] = f2bf(v[0]);
    tile[c * 65 + x + 1] = f2bf(v[1]);
    tile[c * 65 + x + 2] = f2bf(v[2]);
    tile[c * 65 + x + 3] = f2bf(v[3]);
  }
  __syncthreads();
  ushort_t* orow = outp + ((size_t)(b * W + y) * W) * 256;
#pragma unroll
  for (int i = 0; i < W / 4; ++i) {
    const int idx = t + i * 256;
    const int x = idx >> 6;
    const int c4 = (idx & 63) * 4;
    ushort4_t v;
    v[0] = tile[(c4 + 0) * 65 + x];
    v[1] = tile[(c4 + 1) * 65 + x];
    v[2] = tile[(c4 + 2) * 65 + x];
    v[3] = tile[(c4 + 3) * 65 + x];
    *(ushort4_t*)(orow + (size_t)x * 256 + c4) = v;
  }
}

// ---------------------------------------------------------------------------
// K0 (merged): weights reorder / feature transpose / IoU matching.
// ---------------------------------------------------------------------------
__global__ __launch_bounds__(256) void prep_kernel(
    const float* __restrict__ cw, const float* __restrict__ fw,
    const float* __restrict__ f3, const float* __restrict__ f4,
    const float* __restrict__ f5, const float* __restrict__ p3,
    const float* __restrict__ p4, const float* __restrict__ p5,
    const float* __restrict__ gt, ushort_t* __restrict__ wr,
    ushort_t* __restrict__ fwb, ushort_t* __restrict__ cl3,
    ushort_t* __restrict__ cl4, ushort_t* __restrict__ cl5,
    float* __restrict__ out) {
  __shared__ ushort_t tile[256 * 65];  // [c][x], pitch 65 -> 2-way max (free)
  const int id = blockIdx.x;
  const int t = threadIdx.x;

  if (id < 512) {
    // ---- conv weights: chunk-major ----
    const int i0 = id * 256 + t;
    const int stride = 512 * 256;
    for (int idx = i0; idx < WCONV_ELEMS; idx += stride) {
      const int kk = idx >> 12;
      const int rem = idx & 4095;
      const int co = rem >> 4;
      const int i = rem & 15;
      const int k = kk * 16 + i;
      const int j = k >> 8;
      const int ci = k & 255;
      wr[idx] = f2bf(cw[(co * 256 + ci) * 9 + j]);
    }
    // ---- fc weights: A-fragment order, 32 padded class rows ----
    for (int idx = i0; idx < WFC2_ELEMS; idx += stride) {
      const int kb = idx >> 10;
      const int rem = idx & 1023;
      const int cls = rem >> 5;
      const int koff = rem & 31;
      fwb[idx] =
          (cls < NCLS) ? f2bf(fw[(size_t)cls * 12544 + kb * 32 + koff]) : 0;
    }
  } else if (id < 960) {
    // ---- features NCHW -> NHWC bf16 (compile-time W specialization) ----
    const int fid = id - 512;
    if (fid < 256)      transpose_feat<64>(f3, cl3, fid, t, tile);
    else if (fid < 384) transpose_feat<32>(f4, cl4, fid - 256, t, tile);
    else                transpose_feat<16>(f5, cl5, fid - 384, t, tile);
  } else {
    // ---- matching ----
    const int gidx = (id - 960) * 256 + t;
    if (gidx >= NROI_TOT) return;
    const int b = gidx / PROPS_PER_IMG;
    const int i = gidx - b * PROPS_PER_IMG;
    const int lvl = i >> 8;
    const int r = i & 255;
    const float* prop =
        (lvl == 0 ? p3 : (lvl == 1 ? p4 : p5)) + (size_t)(b * R_ + r) * 4;
    const float px1 = prop[0], py1 = prop[1], px2 = prop[2], py2 = prop[3];
    const float a1 = (px2 - px1) * (py2 - py1);
    const float* gtb = gt + (size_t)b * M_ * 5;

    float best = -2.f;
    int bi = 0;
    for (int j = 0; j < M_; ++j) {
      const float gx1 = gtb[j * 5 + 0], gy1 = gtb[j * 5 + 1];
      const float gx2 = gtb[j * 5 + 2], gy2 = gtb[j * 5 + 3];
      const float cls = gtb[j * 5 + 4];
      const float tlx = fmaxf(px1, gx1), tly = fmaxf(py1, gy1);
      const float brx = fminf(px2, gx2), bry = fminf(py2, gy2);
      const float iw = fmaxf(brx - tlx, 0.f), ih = fmaxf(bry - tly, 0.f);
      const float inter = iw * ih;
      const float a2 = (gx2 - gx1) * (gy2 - gy1);
      const float iou = inter / ((a1 + a2) - inter);
      const float m = (cls != -1.0f) ? iou : -1.0f;
      if (m > best) { best = m; bi = j; }
    }
    float o0, o1, o2, o3, o4;
    if (best <= 0.4f) {
      o0 = o1 = o2 = o3 = o4 = -1.0f;
    } else if (best < 0.6f) {
      o0 = o1 = o2 = o3 = o4 = -1e8f;
    } else {
      o0 = gtb[bi * 5 + 0]; o1 = gtb[bi * 5 + 1]; o2 = gtb[bi * 5 + 2];
      o3 = gtb[bi * 5 + 3]; o4 = gtb[bi * 5 + 4];
    }
    float* od = out + (size_t)NROI_TOT * NCLS + (size_t)gidx * 5;
    od[0] = o0; od[1] = o1; od[2] = o2; od[3] = o3; od[4] = o4;
  }
}

// ---------------------------------------------------------------------------
// K1: fused roi-align -> MFMA conv3x3 -> relu -> MFMA FC. 3 rois per block
//     (1024 blocks); 2 blocks/CU. R6: XOR-swizzled pool columns (see ledger).
// ---------------------------------------------------------------------------
__global__ __launch_bounds__(512, 4) void cls_head_kernel(
    const ushort_t* __restrict__ cl3, const ushort_t* __restrict__ cl4,
    const ushort_t* __restrict__ cl5, const float* __restrict__ p3,
    const float* __restrict__ p4, const float* __restrict__ p5,
    const ushort_t* __restrict__ wr, const float* __restrict__ conv_b,
    const ushort_t* __restrict__ fwb, const float* __restrict__ fc_b,
    float* __restrict__ out) {
  __shared__ __align__(16) ushort_t s_pool[POOL_ROWS * POOL_PITCH];  // 78,144 B
  __shared__ union SU {
    struct {
      int iy0[42], iy1[42], ix0[42], ix1[42];
      float ly[42], lx[42], vy[42], vx[42];
    } tb;                      // 1,344 B, dead after roi-align
    float fcred[NCLS * 3 * 8]; // 2,016 B, used in FC phase
  } s_u;

  const int bid = blockIdx.x;
  const int t = threadIdx.x;

  // XCD-locality swizzle: blocks with (bid&7)>>1 == img handle image img.
  const int img = (bid & 7) >> 1;
  const int grp = (bid >> 3) * 2 + (bid & 1);  // 0..255 within image
  const int rid0 = img * PROPS_PER_IMG + grp * 3;

  // per-roi metadata (named scalars; runtime-index reads via ternary)
  const ushort_t *clb0, *clb1, *clb2;
  const float *pr0, *pr1, *pr2;
  int W0, W1, W2;
#pragma unroll
  for (int rr = 0; rr < 3; ++rr) {
    const int rem = grp * 3 + rr;  // 0..767, image == img for all 3
    const int lvl = rem >> 8;
    const int r = rem & 255;
    const ushort_t* base;
    const float* pp;
    int Wl;
    if (lvl == 0) { base = cl3; pp = p3; Wl = 64; }
    else if (lvl == 1) { base = cl4; pp = p4; Wl = 32; }
    else { base = cl5; pp = p5; Wl = 16; }
    base += (size_t)img * Wl * Wl * 256;
    pp += (size_t)(img * R_ + r) * 4;
    if (rr == 0) { clb0 = base; pr0 = pp; W0 = Wl; }
    else if (rr == 1) { clb1 = base; pr1 = pp; W1 = Wl; }
    else { clb2 = base; pr2 = pp; W2 = Wl; }
  }

  // shared zero row (row 147), fully zeroed -> swizzled reads still hit zeros
  if (t < POOL_PITCH) s_pool[147 * POOL_PITCH + t] = 0;

  // ---- axis tables for all 3 rois -----------------------------------------
  if (t < 84) {
    const int rr = t / 28;
    const int tt = t - rr * 28;
    const float* prop = rr == 0 ? pr0 : (rr == 1 ? pr1 : pr2);
    const int H = rr == 0 ? W0 : (rr == 1 ? W1 : W2);
    const float scale = 1.0f / (float)(H == 64 ? 8 : (H == 32 ? 16 : 32));
    const float bx1 = prop[0], by1 = prop[1], bx2 = prop[2], by2 = prop[3];
    const float ax = bx1 * scale - 0.5f;
    const float ay = by1 * scale - 0.5f;
    const float rw = bx2 * scale - 0.5f - ax;
    const float rh = by2 * scale - 0.5f - ay;
    const int i = (tt < G_) ? tt : (tt - G_);
    const float frac = ((float)i + 0.5f) / (float)G_;
    const int o = rr * G_ + i;
    if (tt < G_) {
      float yy = ay + frac * rh;
      float v = (yy >= -1.0f && yy <= (float)H) ? 1.0f : 0.0f;
      float y = fminf(fmaxf(yy, 0.0f), (float)(H - 1));
      float y0f = floorf(y);
      int y0 = (int)y0f;
      s_u.tb.iy0[o] = y0;
      s_u.tb.iy1[o] = min(y0 + 1, H - 1);
      s_u.tb.ly[o] = y - y0f;
      s_u.tb.vy[o] = v;
    } else {
      float xx = ax + frac * rw;
      float v = (xx >= -1.0f && xx <= (float)H) ? 1.0f : 0.0f;
      float x = fminf(fmaxf(xx, 0.0f), (float)(H - 1));
      float x0f = floorf(x);
      int x0 = (int)x0f;
      s_u.tb.ix0[o] = x0;
      s_u.tb.ix1[o] = min(x0 + 1, H - 1);
      s_u.tb.lx[o] = x - x0f;
      s_u.tb.vx[o] = v;
    }
  }
  __syncthreads();

  const int l = t & 63;
  const int w = t >> 6;  // 0..7

  // ---- roi-align: half-wave per cell, lane = 8 channels, packed f32 math --
  {
    const int hw = l >> 5;        // which cell of the pair
    const int c8 = (l & 31) * 8;  // channel offset
    for (int cb = w * 2; cb < 147; cb += 16) {
      const int cell = cb + hw;
      if (cell >= 147) continue;
      const int rr = (cell >= 98) ? 2 : ((cell >= 49) ? 1 : 0);
      const int pos = cell - rr * 49;
      const int py = pos / 7, px = pos - (pos / 7) * 7;
      const ushort_t* clb = rr == 0 ? clb0 : (rr == 1 ? clb1 : clb2);
      const int W = rr == 0 ? W0 : (rr == 1 ? W1 : W2);
      float2v a01 = {0.f, 0.f}, a23 = {0.f, 0.f};
      float2v a45 = {0.f, 0.f}, a67 = {0.f, 0.f};
#pragma unroll
      for (int sy = 0; sy < 2; ++sy) {
        const int gy = rr * G_ + 2 * py + sy;
        const int iy0 = s_u.tb.iy0[gy], iy1 = s_u.tb.iy1[gy];
        const float ly = s_u.tb.ly[gy], vy = s_u.tb.vy[gy];
        const float hy = 1.0f - ly;
#pragma unroll
        for (int sx = 0; sx < 2; ++sx) {
          const int gx = rr * G_ + 2 * px + sx;
          const int ix0 = s_u.tb.ix0[gx], ix1 = s_u.tb.ix1[gx];
          const float lx = s_u.tb.lx[gx], vx = s_u.tb.vx[gx];
          const float hx = 1.0f - lx;
          const float vv = vy * vx;
          const float w00 = vv * hy * hx, w01 = vv * hy * lx;
          const float w10 = vv * ly * hx, w11 = vv * ly * lx;
          const uint4v u00 = *(const uint4v*)(clb + ((size_t)(iy0 * W + ix0) * 256 + c8));
          const uint4v u01 = *(const uint4v*)(clb + ((size_t)(iy0 * W + ix1) * 256 + c8));
          const uint4v u10 = *(const uint4v*)(clb + ((size_t)(iy1 * W + ix0) * 256 + c8));
          const uint4v u11 = *(const uint4v*)(clb + ((size_t)(iy1 * W + ix1) * 256 + c8));
          a01 += cvt2(u00[0]) * w00 + cvt2(u01[0]) * w01 +
                 cvt2(u10[0]) * w10 + cvt2(u11[0]) * w11;
          a23 += cvt2(u00[1]) * w00 + cvt2(u01[1]) * w01 +
                 cvt2(u10[1]) * w10 + cvt2(u11[1]) * w11;
          a45 += cvt2(u00[2]) * w00 + cvt2(u01[2]) * w01 +
                 cvt2(u10[2]) * w10 + cvt2(u11[2]) * w11;
          a67 += cvt2(u00[3]) * w00 + cvt2(u01[3]) * w01 +
                 cvt2(u10[3]) * w10 + cvt2(u11[3]) * w11;
        }
      }
      short8 pv;
      pv[0] = (short)f2bf(a01[0] * 0.25f);
      pv[1] = (short)f2bf(a01[1] * 0.25f);
      pv[2] = (short)f2bf(a23[0] * 0.25f);
      pv[3] = (short)f2bf(a23[1] * 0.25f);
      pv[4] = (short)f2bf(a45[0] * 0.25f);
      pv[5] = (short)f2bf(a45[1] * 0.25f);
      pv[6] = (short)f2bf(a67[0] * 0.25f);
      pv[7] = (short)f2bf(a67[1] * 0.25f);
      *(short8*)&s_pool[cell * POOL_PITCH + pswz(cell, c8)] = pv;
    }
  }
  __syncthreads();  // pool + zero row visible to all waves

  // ---- MFMA conv: wave = 32 co x 5 pos-tiles (147 positions of 3 rois) ----
  const int ml = l & 31;
  const int quad = l >> 5;
  const int co_base = w * 32;

  int gp_[5], py_[5], px_[5];
  bool ok_[5];
#pragma unroll
  for (int tt = 0; tt < 5; ++tt) {
    const int gp = tt * 32 + ml;
    gp_[tt] = gp;
    ok_[tt] = gp < 147;
    const int rr = (gp >= 98) ? 2 : ((gp >= 49) ? 1 : 0);
    const int pos = gp - rr * 49;
    py_[tt] = pos / 7;
    px_[tt] = pos - (pos / 7) * 7;
  }

  floatx16 acc[5];
#pragma unroll
  for (int a = 0; a < 5; ++a)
#pragma unroll
    for (int i = 0; i < 16; ++i) acc[a][i] = 0.f;

  const ushort_t* a0p = wr + (co_base + ml) * 16 + quad * 8;

  int kk = 0;
  for (int j = 0; j < 9; ++j) {
    const int dy = j / 3 - 1, dx = j % 3 - 1;
    int rowb[5], swm[5];
#pragma unroll
    for (int tt = 0; tt < 5; ++tt) {
      const int ry = py_[tt] + dy, rx = px_[tt] + dx;
      const bool okn = ok_[tt] & (ry >= 0) & (ry < 7) & (rx >= 0) & (rx < 7);
      const int bn = okn ? gp_[tt] + dy * 7 + dx : 147;  // row gp' = rr*49+pos'
      rowb[tt] = bn * POOL_PITCH;
      swm[tt] = ((bn >> 3) & 3) << 4;  // column swizzle mask (ushorts)
    }

#pragma unroll 4
    for (int kc = 0; kc < 16; ++kc, ++kk) {
      const short8 a0 = *(const short8*)(a0p + kk * 4096);
      const int cof = kc * 16 + quad * 8;
#pragma unroll
      for (int tt = 0; tt < 5; ++tt) {
        const short8 bv = *(const short8*)&s_pool[rowb[tt] + (cof ^ swm[tt])];
        acc[tt] =
            __builtin_amdgcn_mfma_f32_32x32x16_bf16(a0, bv, acc[tt], 0, 0, 0);
      }
    }
  }
  __syncthreads();  // all pool reads done before h overwrites it

  // ---- epilogue: bias + relu -> h in LDS (fc-k order: [rr][co*49+pos]) ----
  ushort_t* h_lds = s_pool;
  float cbv[16];
#pragma unroll
  for (int reg = 0; reg < 16; ++reg)
    cbv[reg] = conv_b[co_base + (reg & 3) + 8 * (reg >> 2) + 4 * quad];
#pragma unroll
  for (int tt = 0; tt < 5; ++tt) {
    if (ok_[tt]) {
      const int gp = gp_[tt];
      const int rr = (gp >= 98) ? 2 : ((gp >= 49) ? 1 : 0);
      const int hbase = rr * 12544 + (gp - rr * 49);
#pragma unroll
      for (int reg = 0; reg < 16; ++reg) {
        const int co = co_base + (reg & 3) + 8 * (reg >> 2) + 4 * quad;
        h_lds[hbase + co * 49] = f2bf(fmaxf(acc[tt][reg] + cbv[reg], 0.f));
      }
    }
  }
  __syncthreads();

  // ---- FC(12544 -> 21) via MFMA 16x16x32, K-split across 8 waves ----------
  // A from fwb fragment order (coalesced 1 KB/wave); B cols 0..2 = rois 0..2.
  {
    const int n = l & 15;        // C/D col; valid cols 0..2
    const int kq = l >> 4;       // 0..3
    const ushort_t* ap0 = fwb + (n * 4 + kq) * 8;
    const ushort_t* ap1 = ap0 + 512;
    const int rb = (n < 3) ? n : 0;  // clamp B-col source to valid h range
    const ushort_t* bp = h_lds + (size_t)rb * 12544 + kq * 8;
    const int kb0 = w * 49;

    floatx4 fa0, fa1;
#pragma unroll
    for (int i = 0; i < 4; ++i) { fa0[i] = 0.f; fa1[i] = 0.f; }

    for (int it = 0; it < 49; ++it) {
      const int kb = kb0 + it;
      const short8 av0 = *(const short8*)(ap0 + kb * 1024);
      const short8 av1 = *(const short8*)(ap1 + kb * 1024);
      const short8 bv = *(const short8*)(bp + kb * 32);
      fa0 = __builtin_amdgcn_mfma_f32_16x16x32_bf16(av0, bv, fa0, 0, 0, 0);
      fa1 = __builtin_amdgcn_mfma_f32_16x16x32_bf16(av1, bv, fa1, 0, 0, 0);
    }
    // C/D layout: col = l&15, row = (l>>4)*4 + reg
    if (n < 3) {
      const int m4 = kq * 4;
#pragma unroll
      for (int reg = 0; reg < 4; ++reg) {
        const int cls0 = m4 + reg;
        const int cls1 = 16 + m4 + reg;
        s_u.fcred[(cls0 * 3 + n) * 8 + w] = fa0[reg];
        if (cls1 < NCLS) s_u.fcred[(cls1 * 3 + n) * 8 + w] = fa1[reg];
      }
    }
  }
  __syncthreads();
  if (t < 3 * NCLS) {
    const int cls = t / 3;
    const int rr = t - cls * 3;
    const float* pr = &s_u.fcred[(cls * 3 + rr) * 8];
    float s = pr[0] + pr[1] + pr[2] + pr[3] + pr[4] + pr[5] + pr[6] + pr[7];
    out[(size_t)(rid0 + rr) * NCLS + cls] = s + fc_b[cls];
  }
}

extern "C" void kernel_launch(void* const* d_in, const int* in_sizes, int n_in,
                              void* d_out, int out_size, void* d_ws,
                              size_t ws_size, hipStream_t stream) {
  const float* f3 = (const float*)d_in[0];
  const float* f4 = (const float*)d_in[1];
  const float* f5 = (const float*)d_in[2];
  const float* p3 = (const float*)d_in[3];
  const float* p4 = (const float*)d_in[4];
  const float* p5 = (const float*)d_in[5];
  const float* gt = (const float*)d_in[6];
  const float* cw = (const float*)d_in[7];
  const float* cb = (const float*)d_in[8];
  const float* fw = (const float*)d_in[9];
  const float* fb = (const float*)d_in[10];
  float* out = (float*)d_out;

  ushort_t* wsp = (ushort_t*)d_ws;
  ushort_t* wr = wsp;
  ushort_t* fwb = wsp + OFF_FWB;
  ushort_t* cl3 = wsp + OFF_CL3;
  ushort_t* cl4 = wsp + OFF_CL4;
  ushort_t* cl5 = wsp + OFF_CL5;

  prep_kernel<<<972, 256, 0, stream>>>(cw, fw, f3, f4, f5, p3, p4, p5, gt, wr,
                                       fwb, cl3, cl4, cl5, out);
  cls_head_kernel<<<NROI_TOT / 3, 512, 0, stream>>>(cl3, cl4, cl5, p3, p4, p5,
                                                    wr, cb, fwb, fb, out);
}

// Round 7
// 323.428 us; speedup vs baseline: 1.0111x; 1.0111x over previous
//
#include <hip/hip_runtime.h>

typedef unsigned short ushort_t;
typedef __attribute__((ext_vector_type(4))) unsigned short ushort4_t;
typedef __attribute__((ext_vector_type(8))) short short8;
typedef __attribute__((ext_vector_type(4))) unsigned int uint4v;
typedef __attribute__((ext_vector_type(2))) float float2v;
typedef __attribute__((ext_vector_type(4))) float floatx4;
typedef __attribute__((ext_vector_type(16))) float floatx16;

#define B_ 4
#define C_ 256
#define R_ 256
#define M_ 40
#define NCLS 21
#define ROI_ 7
#define G_ 14
#define NROI_TOT 3072
#define PROPS_PER_IMG 768
#define POOL_PITCH 264   // ushorts per pool row (528 B, 16B-aligned) [R8 proven best]
#define POOL_ROWS 148    // 3 rois x 49 positions + 1 shared zero row
#define WCONV_ELEMS (256 * 2304)   // = 144 chunks * 4096
#define NKB 392                    // 12544 / 32 k-blocks for FC
#define WFC2_ELEMS (NKB * 32 * 32) // padded 32 classes, fragment-ordered
// ws layout (ushort offsets)
#define OFF_FWB   WCONV_ELEMS
#define OFF_CL3   (OFF_FWB + WFC2_ELEMS)
#define OFF_CL4   (OFF_CL3 + 4 * 64 * 64 * 256)
#define OFF_CL5   (OFF_CL4 + 4 * 32 * 32 * 256)

// LEDGER (falsified experiments — do not retry):
//  R3 stagger (per-CU ticket + 18us sleep): +8 us. Forced de-phasing only
//     added idle; natural drift already interleaves co-resident blocks.
//  R4 fp32 feature staging: VALU drop as predicted, but FETCH 18.3->32 MB
//     (features 2.6->5.2 MB/img vs 4 MiB XCD L2) -> net +19 us.
//  R5 calibration: identical code re-bench spread ~2.7% (247.4 vs 254.1).
//  R6 pool XOR swizzle: conflicts 1.73e7->3.68e7 (DOUBLED), VALUBusy +7pp,
//     dur +6 us. Row term 4*bn mod 32 is g-invariant (32g==0); the conv
//     B-read's per-bank load is already uniform (8 acc/bank/instr,
//     irreducible for 64 lanes x 16B on 32 banks). The 1.73e7 counter is
//     inherent to this access shape, not removable aliasing.
// Verdict: this kernel (3-roi blocks, bf16 NHWC staging, no swizzle) is the
// measured optimum of the structure: cls_head 247-254 us, total 319-326 us.
// No single counter shows a binding pipe (HBM 0.9%, Mfma 38%, VALU 36%);
// residual is phase serialization + L2 streams. Further gains need a
// phase-overlap rewrite (wave specialization), not parameter tuning.

__device__ __forceinline__ ushort_t f2bf(float f) {
  unsigned u = __builtin_bit_cast(unsigned, f);
  u += 0x7fff + ((u >> 16) & 1);  // RNE
  return (ushort_t)(u >> 16);
}
// two packed bf16 (one dword) -> float2 {low half, high half}
__device__ __forceinline__ float2v cvt2(unsigned u) {
  float2v r;
  r[0] = __builtin_bit_cast(float, u << 16);
  r[1] = __builtin_bit_cast(float, u & 0xffff0000u);
  return r;
}

// ---------------------------------------------------------------------------
// NCHW fp32 -> NHWC bf16 transpose for one (b, y) feature row, compile-time W.
// ---------------------------------------------------------------------------
template <int W>
__device__ __forceinline__ void transpose_feat(const float* __restrict__ in,
                                               ushort_t* __restrict__ outp,
                                               const int fid, const int t,
                                               ushort_t* __restrict__ tile) {
  const int b = fid / W;
  const int y = fid - b * W;
  const float* src = in + (size_t)(b * 256) * (W * W) + (size_t)y * W;
#pragma unroll
  for (int i = 0; i < W / 4; ++i) {
    const int f4 = t + i * 256;
    const int c = f4 / (W / 4);
    const int x = (f4 - c * (W / 4)) * 4;
    const floatx4 v = *(const floatx4*)(src + (size_t)c * (W * W) + x);
    tile[c * 65 + x + 0] = f2bf(v[0]);
    tile[c * 65 + x + 1] = f2bf(v[1]);
    tile[c * 65 + x + 2] = f2bf(v[2]);
    tile[c * 65 + x + 3] = f2bf(v[3]);
  }
  __syncthreads();
  ushort_t* orow = outp + ((size_t)(b * W + y) * W) * 256;
#pragma unroll
  for (int i = 0; i < W / 4; ++i) {
    const int idx = t + i * 256;
    const int x = idx >> 6;
    const int c4 = (idx & 63) * 4;
    ushort4_t v;
    v[0] = tile[(c4 + 0) * 65 + x];
    v[1] = tile[(c4 + 1) * 65 + x];
    v[2] = tile[(c4 + 2) * 65 + x];
    v[3] = tile[(c4 + 3) * 65 + x];
    *(ushort4_t*)(orow + (size_t)x * 256 + c4) = v;
  }
}

// ---------------------------------------------------------------------------
// K0 (merged): weights reorder / feature transpose / IoU matching.
// ---------------------------------------------------------------------------
__global__ __launch_bounds__(256) void prep_kernel(
    const float* __restrict__ cw, const float* __restrict__ fw,
    const float* __restrict__ f3, const float* __restrict__ f4,
    const float* __restrict__ f5, const float* __restrict__ p3,
    const float* __restrict__ p4, const float* __restrict__ p5,
    const float* __restrict__ gt, ushort_t* __restrict__ wr,
    ushort_t* __restrict__ fwb, ushort_t* __restrict__ cl3,
    ushort_t* __restrict__ cl4, ushort_t* __restrict__ cl5,
    float* __restrict__ out) {
  __shared__ ushort_t tile[256 * 65];  // [c][x], pitch 65 -> 2-way max (free)
  const int id = blockIdx.x;
  const int t = threadIdx.x;

  if (id < 512) {
    // ---- conv weights: chunk-major ----
    const int i0 = id * 256 + t;
    const int stride = 512 * 256;
    for (int idx = i0; idx < WCONV_ELEMS; idx += stride) {
      const int kk = idx >> 12;
      const int rem = idx & 4095;
      const int co = rem >> 4;
      const int i = rem & 15;
      const int k = kk * 16 + i;
      const int j = k >> 8;
      const int ci = k & 255;
      wr[idx] = f2bf(cw[(co * 256 + ci) * 9 + j]);
    }
    // ---- fc weights: A-fragment order, 32 padded class rows ----
    for (int idx = i0; idx < WFC2_ELEMS; idx += stride) {
      const int kb = idx >> 10;
      const int rem = idx & 1023;
      const int cls = rem >> 5;
      const int koff = rem & 31;
      fwb[idx] =
          (cls < NCLS) ? f2bf(fw[(size_t)cls * 12544 + kb * 32 + koff]) : 0;
    }
  } else if (id < 960) {
    // ---- features NCHW -> NHWC bf16 (compile-time W specialization) ----
    const int fid = id - 512;
    if (fid < 256)      transpose_feat<64>(f3, cl3, fid, t, tile);
    else if (fid < 384) transpose_feat<32>(f4, cl4, fid - 256, t, tile);
    else                transpose_feat<16>(f5, cl5, fid - 384, t, tile);
  } else {
    // ---- matching ----
    const int gidx = (id - 960) * 256 + t;
    if (gidx >= NROI_TOT) return;
    const int b = gidx / PROPS_PER_IMG;
    const int i = gidx - b * PROPS_PER_IMG;
    const int lvl = i >> 8;
    const int r = i & 255;
    const float* prop =
        (lvl == 0 ? p3 : (lvl == 1 ? p4 : p5)) + (size_t)(b * R_ + r) * 4;
    const float px1 = prop[0], py1 = prop[1], px2 = prop[2], py2 = prop[3];
    const float a1 = (px2 - px1) * (py2 - py1);
    const float* gtb = gt + (size_t)b * M_ * 5;

    float best = -2.f;
    int bi = 0;
    for (int j = 0; j < M_; ++j) {
      const float gx1 = gtb[j * 5 + 0], gy1 = gtb[j * 5 + 1];
      const float gx2 = gtb[j * 5 + 2], gy2 = gtb[j * 5 + 3];
      const float cls = gtb[j * 5 + 4];
      const float tlx = fmaxf(px1, gx1), tly = fmaxf(py1, gy1);
      const float brx = fminf(px2, gx2), bry = fminf(py2, gy2);
      const float iw = fmaxf(brx - tlx, 0.f), ih = fmaxf(bry - tly, 0.f);
      const float inter = iw * ih;
      const float a2 = (gx2 - gx1) * (gy2 - gy1);
      const float iou = inter / ((a1 + a2) - inter);
      const float m = (cls != -1.0f) ? iou : -1.0f;
      if (m > best) { best = m; bi = j; }
    }
    float o0, o1, o2, o3, o4;
    if (best <= 0.4f) {
      o0 = o1 = o2 = o3 = o4 = -1.0f;
    } else if (best < 0.6f) {
      o0 = o1 = o2 = o3 = o4 = -1e8f;
    } else {
      o0 = gtb[bi * 5 + 0]; o1 = gtb[bi * 5 + 1]; o2 = gtb[bi * 5 + 2];
      o3 = gtb[bi * 5 + 3]; o4 = gtb[bi * 5 + 4];
    }
    float* od = out + (size_t)NROI_TOT * NCLS + (size_t)gidx * 5;
    od[0] = o0; od[1] = o1; od[2] = o2; od[3] = o3; od[4] = o4;
  }
}

// ---------------------------------------------------------------------------
// K1: fused roi-align -> MFMA conv3x3 -> relu -> MFMA FC. 3 rois per block
//     (1024 blocks); 2 blocks/CU (LDS+VGPR locked). Measured optimum.
// ---------------------------------------------------------------------------
__global__ __launch_bounds__(512, 4) void cls_head_kernel(
    const ushort_t* __restrict__ cl3, const ushort_t* __restrict__ cl4,
    const ushort_t* __restrict__ cl5, const float* __restrict__ p3,
    const float* __restrict__ p4, const float* __restrict__ p5,
    const ushort_t* __restrict__ wr, const float* __restrict__ conv_b,
    const ushort_t* __restrict__ fwb, const float* __restrict__ fc_b,
    float* __restrict__ out) {
  __shared__ __align__(16) ushort_t s_pool[POOL_ROWS * POOL_PITCH];  // 78,144 B
  __shared__ union SU {
    struct {
      int iy0[42], iy1[42], ix0[42], ix1[42];
      float ly[42], lx[42], vy[42], vx[42];
    } tb;                      // 1,344 B, dead after roi-align
    float fcred[NCLS * 3 * 8]; // 2,016 B, used in FC phase
  } s_u;

  const int bid = blockIdx.x;
  const int t = threadIdx.x;

  // XCD-locality swizzle: blocks with (bid&7)>>1 == img handle image img.
  const int img = (bid & 7) >> 1;
  const int grp = (bid >> 3) * 2 + (bid & 1);  // 0..255 within image
  const int rid0 = img * PROPS_PER_IMG + grp * 3;

  // per-roi metadata (named scalars; runtime-index reads via ternary)
  const ushort_t *clb0, *clb1, *clb2;
  const float *pr0, *pr1, *pr2;
  int W0, W1, W2;
#pragma unroll
  for (int rr = 0; rr < 3; ++rr) {
    const int rem = grp * 3 + rr;  // 0..767, image == img for all 3
    const int lvl = rem >> 8;
    const int r = rem & 255;
    const ushort_t* base;
    const float* pp;
    int Wl;
    if (lvl == 0) { base = cl3; pp = p3; Wl = 64; }
    else if (lvl == 1) { base = cl4; pp = p4; Wl = 32; }
    else { base = cl5; pp = p5; Wl = 16; }
    base += (size_t)img * Wl * Wl * 256;
    pp += (size_t)(img * R_ + r) * 4;
    if (rr == 0) { clb0 = base; pr0 = pp; W0 = Wl; }
    else if (rr == 1) { clb1 = base; pr1 = pp; W1 = Wl; }
    else { clb2 = base; pr2 = pp; W2 = Wl; }
  }

  // shared zero row (row 147); conv reads cols < 256
  if (t < POOL_PITCH) s_pool[147 * POOL_PITCH + t] = 0;

  // ---- axis tables for all 3 rois -----------------------------------------
  if (t < 84) {
    const int rr = t / 28;
    const int tt = t - rr * 28;
    const float* prop = rr == 0 ? pr0 : (rr == 1 ? pr1 : pr2);
    const int H = rr == 0 ? W0 : (rr == 1 ? W1 : W2);
    const float scale = 1.0f / (float)(H == 64 ? 8 : (H == 32 ? 16 : 32));
    const float bx1 = prop[0], by1 = prop[1], bx2 = prop[2], by2 = prop[3];
    const float ax = bx1 * scale - 0.5f;
    const float ay = by1 * scale - 0.5f;
    const float rw = bx2 * scale - 0.5f - ax;
    const float rh = by2 * scale - 0.5f - ay;
    const int i = (tt < G_) ? tt : (tt - G_);
    const float frac = ((float)i + 0.5f) / (float)G_;
    const int o = rr * G_ + i;
    if (tt < G_) {
      float yy = ay + frac * rh;
      float v = (yy >= -1.0f && yy <= (float)H) ? 1.0f : 0.0f;
      float y = fminf(fmaxf(yy, 0.0f), (float)(H - 1));
      float y0f = floorf(y);
      int y0 = (int)y0f;
      s_u.tb.iy0[o] = y0;
      s_u.tb.iy1[o] = min(y0 + 1, H - 1);
      s_u.tb.ly[o] = y - y0f;
      s_u.tb.vy[o] = v;
    } else {
      float xx = ax + frac * rw;
      float v = (xx >= -1.0f && xx <= (float)H) ? 1.0f : 0.0f;
      float x = fminf(fmaxf(xx, 0.0f), (float)(H - 1));
      float x0f = floorf(x);
      int x0 = (int)x0f;
      s_u.tb.ix0[o] = x0;
      s_u.tb.ix1[o] = min(x0 + 1, H - 1);
      s_u.tb.lx[o] = x - x0f;
      s_u.tb.vx[o] = v;
    }
  }
  __syncthreads();

  const int l = t & 63;
  const int w = t >> 6;  // 0..7

  // ---- roi-align: half-wave per cell, lane = 8 channels, packed f32 math --
  {
    const int hw = l >> 5;        // which cell of the pair
    const int c8 = (l & 31) * 8;  // channel offset
    for (int cb = w * 2; cb < 147; cb += 16) {
      const int cell = cb + hw;
      if (cell >= 147) continue;
      const int rr = (cell >= 98) ? 2 : ((cell >= 49) ? 1 : 0);
      const int pos = cell - rr * 49;
      const int py = pos / 7, px = pos - (pos / 7) * 7;
      const ushort_t* clb = rr == 0 ? clb0 : (rr == 1 ? clb1 : clb2);
      const int W = rr == 0 ? W0 : (rr == 1 ? W1 : W2);
      float2v a01 = {0.f, 0.f}, a23 = {0.f, 0.f};
      float2v a45 = {0.f, 0.f}, a67 = {0.f, 0.f};
#pragma unroll
      for (int sy = 0; sy < 2; ++sy) {
        const int gy = rr * G_ + 2 * py + sy;
        const int iy0 = s_u.tb.iy0[gy], iy1 = s_u.tb.iy1[gy];
        const float ly = s_u.tb.ly[gy], vy = s_u.tb.vy[gy];
        const float hy = 1.0f - ly;
#pragma unroll
        for (int sx = 0; sx < 2; ++sx) {
          const int gx = rr * G_ + 2 * px + sx;
          const int ix0 = s_u.tb.ix0[gx], ix1 = s_u.tb.ix1[gx];
          const float lx = s_u.tb.lx[gx], vx = s_u.tb.vx[gx];
          const float hx = 1.0f - lx;
          const float vv = vy * vx;
          const float w00 = vv * hy * hx, w01 = vv * hy * lx;
          const float w10 = vv * ly * hx, w11 = vv * ly * lx;
          const uint4v u00 = *(const uint4v*)(clb + ((size_t)(iy0 * W + ix0) * 256 + c8));
          const uint4v u01 = *(const uint4v*)(clb + ((size_t)(iy0 * W + ix1) * 256 + c8));
          const uint4v u10 = *(const uint4v*)(clb + ((size_t)(iy1 * W + ix0) * 256 + c8));
          const uint4v u11 = *(const uint4v*)(clb + ((size_t)(iy1 * W + ix1) * 256 + c8));
          a01 += cvt2(u00[0]) * w00 + cvt2(u01[0]) * w01 +
                 cvt2(u10[0]) * w10 + cvt2(u11[0]) * w11;
          a23 += cvt2(u00[1]) * w00 + cvt2(u01[1]) * w01 +
                 cvt2(u10[1]) * w10 + cvt2(u11[1]) * w11;
          a45 += cvt2(u00[2]) * w00 + cvt2(u01[2]) * w01 +
                 cvt2(u10[2]) * w10 + cvt2(u11[2]) * w11;
          a67 += cvt2(u00[3]) * w00 + cvt2(u01[3]) * w01 +
                 cvt2(u10[3]) * w10 + cvt2(u11[3]) * w11;
        }
      }
      short8 pv;
      pv[0] = (short)f2bf(a01[0] * 0.25f);
      pv[1] = (short)f2bf(a01[1] * 0.25f);
      pv[2] = (short)f2bf(a23[0] * 0.25f);
      pv[3] = (short)f2bf(a23[1] * 0.25f);
      pv[4] = (short)f2bf(a45[0] * 0.25f);
      pv[5] = (short)f2bf(a45[1] * 0.25f);
      pv[6] = (short)f2bf(a67[0] * 0.25f);
      pv[7] = (short)f2bf(a67[1] * 0.25f);
      *(short8*)&s_pool[cell * POOL_PITCH + c8] = pv;
    }
  }
  __syncthreads();  // pool + zero row visible to all waves

  // ---- MFMA conv: wave = 32 co x 5 pos-tiles (147 positions of 3 rois) ----
  const int ml = l & 31;
  const int quad = l >> 5;
  const int co_base = w * 32;

  int gp_[5], py_[5], px_[5];
  bool ok_[5];
#pragma unroll
  for (int tt = 0; tt < 5; ++tt) {
    const int gp = tt * 32 + ml;
    gp_[tt] = gp;
    ok_[tt] = gp < 147;
    const int rr = (gp >= 98) ? 2 : ((gp >= 49) ? 1 : 0);
    const int pos = gp - rr * 49;
    py_[tt] = pos / 7;
    px_[tt] = pos - (pos / 7) * 7;
  }

  floatx16 acc[5];
#pragma unroll
  for (int a = 0; a < 5; ++a)
#pragma unroll
    for (int i = 0; i < 16; ++i) acc[a][i] = 0.f;

  const ushort_t* a0p = wr + (co_base + ml) * 16 + quad * 8;

  int kk = 0;
  for (int j = 0; j < 9; ++j) {
    const int dy = j / 3 - 1, dx = j % 3 - 1;
    int bn[5];
#pragma unroll
    for (int tt = 0; tt < 5; ++tt) {
      const int ry = py_[tt] + dy, rx = px_[tt] + dx;
      const bool okn = ok_[tt] & (ry >= 0) & (ry < 7) & (rx >= 0) & (rx < 7);
      bn[tt] = okn ? gp_[tt] + dy * 7 + dx : 147;  // row gp' = rr*49+pos'
    }

#pragma unroll 4
    for (int kc = 0; kc < 16; ++kc, ++kk) {
      const short8 a0 = *(const short8*)(a0p + kk * 4096);
      const int cof = kc * 16 + quad * 8;
#pragma unroll
      for (int tt = 0; tt < 5; ++tt) {
        const short8 bv = *(const short8*)&s_pool[bn[tt] * POOL_PITCH + cof];
        acc[tt] =
            __builtin_amdgcn_mfma_f32_32x32x16_bf16(a0, bv, acc[tt], 0, 0, 0);
      }
    }
  }
  __syncthreads();  // all pool reads done before h overwrites it

  // ---- epilogue: bias + relu -> h in LDS (fc-k order: [rr][co*49+pos]) ----
  ushort_t* h_lds = s_pool;
  float cbv[16];
#pragma unroll
  for (int reg = 0; reg < 16; ++reg)
    cbv[reg] = conv_b[co_base + (reg & 3) + 8 * (reg >> 2) + 4 * quad];
#pragma unroll
  for (int tt = 0; tt < 5; ++tt) {
    if (ok_[tt]) {
      const int gp = gp_[tt];
      const int rr = (gp >= 98) ? 2 : ((gp >= 49) ? 1 : 0);
      const int hbase = rr * 12544 + (gp - rr * 49);
#pragma unroll
      for (int reg = 0; reg < 16; ++reg) {
        const int co = co_base + (reg & 3) + 8 * (reg >> 2) + 4 * quad;
        h_lds[hbase + co * 49] = f2bf(fmaxf(acc[tt][reg] + cbv[reg], 0.f));
      }
    }
  }
  __syncthreads();

  // ---- FC(12544 -> 21) via MFMA 16x16x32, K-split across 8 waves ----------
  // A from fwb fragment order (coalesced 1 KB/wave); B cols 0..2 = rois 0..2.
  {
    const int n = l & 15;        // C/D col; valid cols 0..2
    const int kq = l >> 4;       // 0..3
    const ushort_t* ap0 = fwb + (n * 4 + kq) * 8;
    const ushort_t* ap1 = ap0 + 512;
    const int rb = (n < 3) ? n : 0;  // clamp B-col source to valid h range
    const ushort_t* bp = h_lds + (size_t)rb * 12544 + kq * 8;
    const int kb0 = w * 49;

    floatx4 fa0, fa1;
#pragma unroll
    for (int i = 0; i < 4; ++i) { fa0[i] = 0.f; fa1[i] = 0.f; }

    for (int it = 0; it < 49; ++it) {
      const int kb = kb0 + it;
      const short8 av0 = *(const short8*)(ap0 + kb * 1024);
      const short8 av1 = *(const short8*)(ap1 + kb * 1024);
      const short8 bv = *(const short8*)(bp + kb * 32);
      fa0 = __builtin_amdgcn_mfma_f32_16x16x32_bf16(av0, bv, fa0, 0, 0, 0);
      fa1 = __builtin_amdgcn_mfma_f32_16x16x32_bf16(av1, bv, fa1, 0, 0, 0);
    }
    // C/D layout: col = l&15, row = (l>>4)*4 + reg
    if (n < 3) {
      const int m4 = kq * 4;
#pragma unroll
      for (int reg = 0; reg < 4; ++reg) {
        const int cls0 = m4 + reg;
        const int cls1 = 16 + m4 + reg;
        s_u.fcred[(cls0 * 3 + n) * 8 + w] = fa0[reg];
        if (cls1 < NCLS) s_u.fcred[(cls1 * 3 + n) * 8 + w] = fa1[reg];
      }
    }
  }
  __syncthreads();
  if (t < 3 * NCLS) {
    const int cls = t / 3;
    const int rr = t - cls * 3;
    const float* pr = &s_u.fcred[(cls * 3 + rr) * 8];
    float s = pr[0] + pr[1] + pr[2] + pr[3] + pr[4] + pr[5] + pr[6] + pr[7];
    out[(size_t)(rid0 + rr) * NCLS + cls] = s + fc_b[cls];
  }
}

extern "C" void kernel_launch(void* const* d_in, const int* in_sizes, int n_in,
                              void* d_out, int out_size, void* d_ws,
                              size_t ws_size, hipStream_t stream) {
  const float* f3 = (const float*)d_in[0];
  const float* f4 = (const float*)d_in[1];
  const float* f5 = (const float*)d_in[2];
  const float* p3 = (const float*)d_in[3];
  const float* p4 = (const float*)d_in[4];
  const float* p5 = (const float*)d_in[5];
  const float* gt = (const float*)d_in[6];
  const float* cw = (const float*)d_in[7];
  const float* cb = (const float*)d_in[8];
  const float* fw = (const float*)d_in[9];
  const float* fb = (const float*)d_in[10];
  float* out = (float*)d_out;

  ushort_t* wsp = (ushort_t*)d_ws;
  ushort_t* wr = wsp;
  ushort_t* fwb = wsp + OFF_FWB;
  ushort_t* cl3 = wsp + OFF_CL3;
  ushort_t* cl4 = wsp + OFF_CL4;
  ushort_t* cl5 = wsp + OFF_CL5;

  prep_kernel<<<972, 256, 0, stream>>>(cw, fw, f3, f4, f5, p3, p4, p5, gt, wr,
                                       fwb, cl3, cl4, cl5, out);
  cls_head_kernel<<<NROI_TOT / 3, 512, 0, stream>>>(cl3, cl4, cl5, p3, p4, p5,
                                                    wr, cb, fwb, fb, out);
}